// Round 4
// baseline (4851.855 us; speedup 1.0000x reference)
//
#include <hip/hip_runtime.h>

#define H 51
#define T_LEN 8192
#define CHUNK 64

__device__ __forceinline__ float fast_sigmoid(float x) {
    float e = __builtin_amdgcn_exp2f(x * -1.44269504088896341f);
    return __builtin_amdgcn_rcpf(1.0f + e);
}

__device__ __forceinline__ float fast_tanh(float x) {
    // tanh(x) = 2/(1+exp(-2x)) - 1 ; rcp(inf)=0 handles saturation.
    float e = __builtin_amdgcn_exp2f(x * -2.88539008177792681f);
    float r = __builtin_amdgcn_rcpf(1.0f + e);
    return fmaf(2.0f, r, -1.0f);
}

__device__ __forceinline__ float bcast_lane(float v, int lane) {
    return __int_as_float(__builtin_amdgcn_readlane(__float_as_int(v), lane));
}

// ---- DPP wave-64 sum, result lands in lane 63 (VALU-class, no LDS) ----
template <int CTRL, int RM>
__device__ __forceinline__ float dpp_add(float v) {
    int t = __builtin_amdgcn_update_dpp(0, __float_as_int(v), CTRL, RM, 0xF, false);
    return v + __int_as_float(t);
}
__device__ __forceinline__ float wave_sum_to_lane63(float v) {
    v = dpp_add<0x111, 0xF>(v);  // row_shr:1
    v = dpp_add<0x112, 0xF>(v);  // row_shr:2
    v = dpp_add<0x114, 0xF>(v);  // row_shr:4
    v = dpp_add<0x118, 0xF>(v);  // row_shr:8  -> lane 16r+15 = row sum
    v = dpp_add<0x142, 0xA>(v);  // row_bcast:15 -> rows 1,3
    v = dpp_add<0x143, 0xC>(v);  // row_bcast:31 -> rows 2,3; lane 63 = total
    return v;
}

// One wave (64 lanes) per batch element. Lane L owns hidden unit L (lanes
// 51..63 hold zeroed weights/biases -> gates 0 -> i=f=o=0.5, g=0 ->
// c'=0.5*c=0, h'=0 -> they contribute 0 to every cross-lane sum).
// h-broadcast is pure v_readlane (no LDS, no barriers anywhere in the loop).
extern "C" __global__ void __launch_bounds__(64, 1)
lstm_fused(const float* __restrict__ input,   // [B, T]
           const float* __restrict__ W_ih,    // [204, 1]
           const float* __restrict__ W_hh,    // [204, 51]
           const float* __restrict__ b_ih,    // [204]
           const float* __restrict__ b_hh,    // [204]
           const float* __restrict__ W_lin,   // [2, 51]
           const float* __restrict__ b_lin,   // [2]
           float* __restrict__ out)           // [B, 2, T]
{
    const int L = threadIdx.x;
    const int b = blockIdx.x;
    const bool act = (L < H);

    // ---- one-time weight load into registers (4 rows of 51 per lane) ----
    float w[4][H];
#pragma unroll
    for (int g = 0; g < 4; ++g) {
#pragma unroll
        for (int k = 0; k < H; ++k) {
            w[g][k] = act ? W_hh[(g * H + L) * H + k] : 0.0f;
        }
    }
    float wi[4], bsum[4];
#pragma unroll
    for (int g = 0; g < 4; ++g) {
        wi[g]   = act ? W_ih[g * H + L] : 0.0f;
        bsum[g] = act ? (b_ih[g * H + L] + b_hh[g * H + L]) : 0.0f;
    }
    const float wl0 = act ? W_lin[L]     : 0.0f;
    const float wl1 = act ? W_lin[H + L] : 0.0f;
    const float bl0 = b_lin[0];
    const float bl1 = b_lin[1];

    float h = 0.0f, c = 0.0f;

    const float* inrow = input + (size_t)b * T_LEN;
    float* out0 = out + (size_t)b * 2 * T_LEN;
    float* out1 = out0 + T_LEN;

    // input prefetch: chunk n+1 loads while chunk n computes (64 steps cover)
    float x_cur = inrow[L];

    for (int t0 = 0; t0 < T_LEN; t0 += CHUNK) {
        float x_next = 0.0f;
        if (t0 + CHUNK < T_LEN) x_next = inrow[t0 + CHUNK + L];
        float v0 = 0.0f, v1 = 0.0f;

#pragma unroll 2
        for (int k = 0; k < CHUNK; ++k) {
            const float xk = bcast_lane(x_cur, k);

            float acc0 = fmaf(xk, wi[0], bsum[0]);
            float acc1 = fmaf(xk, wi[1], bsum[1]);
            float acc2 = fmaf(xk, wi[2], bsum[2]);
            float acc3 = fmaf(xk, wi[3], bsum[3]);
            // matvec: broadcast h[kk] via v_readlane (SGPR), FMA vs per-lane
            // weight VGPRs. 51 readlanes + 204 FMAs, zero memory ops.
#pragma unroll
            for (int kk = 0; kk < H; ++kk) {
                const float hk = bcast_lane(h, kk);
                acc0 = fmaf(hk, w[0][kk], acc0);
                acc1 = fmaf(hk, w[1][kk], acc1);
                acc2 = fmaf(hk, w[2][kk], acc2);
                acc3 = fmaf(hk, w[3][kk], acc3);
            }

            const float ig = fast_sigmoid(acc0);
            const float fg = fast_sigmoid(acc1);
            const float gg = fast_tanh(acc2);
            const float og = fast_sigmoid(acc3);
            c = fmaf(fg, c, ig * gg);
            h = og * fast_tanh(c);

            // output projection: 2 dots over lanes, DPP reduce (off the
            // h(t)->h(t+1) critical path; overlaps next step's matvec)
            float p0 = wave_sum_to_lane63(h * wl0);
            float p1 = wave_sum_to_lane63(h * wl1);
            const float s0 = bcast_lane(p0, 63);
            const float s1 = bcast_lane(p1, 63);
            if (k == L) { v0 = s0 + bl0; v1 = s1 + bl1; }
        }

        out0[t0 + L] = v0;            // coalesced store, 64 steps at once
        out1[t0 + L] = v1;
        x_cur = x_next;
    }
}

extern "C" void kernel_launch(void* const* d_in, const int* in_sizes, int n_in,
                              void* d_out, int out_size, void* d_ws, size_t ws_size,
                              hipStream_t stream) {
    const float* input = (const float*)d_in[0];
    const float* W_ih  = (const float*)d_in[1];
    const float* W_hh  = (const float*)d_in[2];
    const float* b_ih  = (const float*)d_in[3];
    const float* b_hh  = (const float*)d_in[4];
    const float* W_lin = (const float*)d_in[5];
    const float* b_lin = (const float*)d_in[6];
    float* outp = (float*)d_out;

    const int B = in_sizes[0] / T_LEN;   // 1024
    lstm_fused<<<dim3(B), dim3(64), 0, stream>>>(
        input, W_ih, W_hh, b_ih, b_hh, W_lin, b_lin, outp);
}